// Round 7
// baseline (89.090 us; speedup 1.0000x reference)
//
#include <hip/hip_runtime.h>
#include <hip/hip_bf16.h>
#include <math.h>

#define BB 8
#define TT 2048
#define CC 1024
#define HH 64
#define VTS 2112         // padded V^T row stride (4224 B = 4KB + 128B, breaks L2 channel aliasing)
#define WUB 576          // wave-units per batch = sum over qtiles of (qt/16 + 1)
#define NWU (BB * WUB)   // 4608 total wave-units

typedef __attribute__((ext_vector_type(8))) short bf16x8;
typedef __attribute__((ext_vector_type(4))) float f32x4;
typedef __attribute__((ext_vector_type(8))) unsigned short us8;

__device__ __forceinline__ unsigned short f2bf(float f) {
    return __builtin_bit_cast(unsigned short, __float2bfloat16(f));
}

#define GLOAD_LDS16(g, l) \
    __builtin_amdgcn_global_load_lds( \
        (const __attribute__((address_space(1))) void*)(g), \
        (__attribute__((address_space(3))) void*)(l), 16, 0, 0)

// ---------------- W fp32 -> bf16 pre-convert ----------------
__global__ __launch_bounds__(256) void wconv(
    const float* __restrict__ Wq, const float* __restrict__ Wk,
    const float* __restrict__ Wv, unsigned short* __restrict__ wbf)
{
    const int i = blockIdx.x * 256 + threadIdx.x;     // 8-elem group id
    const float* srcs[3] = {Wq, Wk, Wv};
    const float* src = srcs[i >> 13] + (size_t)(i & 8191) * 8;
    float4 a = *(const float4*)(src);
    float4 b = *(const float4*)(src + 4);
    us8 u;
    u[0]=f2bf(a.x); u[1]=f2bf(a.y); u[2]=f2bf(a.z); u[3]=f2bf(a.w);
    u[4]=f2bf(b.x); u[5]=f2bf(b.y); u[6]=f2bf(b.z); u[7]=f2bf(b.w);
    *(us8*)(wbf + (size_t)i * 8) = u;
}

// ---------------- QKV projection: LDS double-buffered MFMA GEMM ----------
// M=16384, N=192, K=1024. BM=64, BN=192, BK=64. 8 waves (4M x 2N), each wave
// 16 rows x 96 cols. Staging via global_load_lds(16B) with XOR-swizzle.
__global__ __launch_bounds__(512) void qkv_proj(
    const float* __restrict__ x,
    const unsigned short* __restrict__ wbf,
    unsigned short* __restrict__ qo,
    unsigned short* __restrict__ ko,
    unsigned short* __restrict__ vt)
{
    __shared__ float xs[2][64 * 64];            // [buf][row(64)][k(64 fp32)]
    __shared__ unsigned short wsl[2][192 * 64]; // [buf][col(192)][k(64 bf16)]

    const int tid = threadIdx.x;
    const int w = tid >> 6, l = tid & 63, lr = l & 15, lg = l >> 4;
    const int wm = w >> 1, wn = w & 1;
    const int row0 = blockIdx.x * 64;

    f32x4 acc[6];
#pragma unroll
    for (int i = 0; i < 6; i++) acc[i] = (f32x4){0.f, 0.f, 0.f, 0.f};

#define STAGE(buf, t)                                                          \
    {                                                                          \
        const int k0 = (t) * 64;                                               \
        _Pragma("unroll")                                                      \
        for (int i = 0; i < 2; i++) {                                          \
            const int ci = w * 128 + i * 64 + l;       /* 0..1023 */           \
            const int r = ci >> 4, c = ci & 15;                                \
            const float* g = x + (size_t)(row0 + r) * CC + k0 +                \
                             ((c ^ (r & 7)) << 2);                             \
            GLOAD_LDS16(g, &xs[buf][ci * 4]);                                  \
        }                                                                      \
        _Pragma("unroll")                                                      \
        for (int i = 0; i < 3; i++) {                                          \
            const int ci = w * 192 + i * 64 + l;       /* 0..1535 */           \
            const int r = ci >> 3, c = ci & 7;                                 \
            const unsigned short* g = wbf + (size_t)r * CC + k0 +              \
                                      ((c ^ (r & 7)) << 3);                    \
            GLOAD_LDS16(g, &wsl[buf][ci * 8]);                                 \
        }                                                                      \
    }

    STAGE(0, 0);
    __syncthreads();

    for (int t = 0; t < 16; t++) {
        const int buf = t & 1;
        if (t < 15) STAGE(buf ^ 1, t + 1);

        const int ar = wm * 16 + lr;
#pragma unroll
        for (int kk = 0; kk < 2; kk++) {
            const int p0 = (kk * 8 + 2 * lg) ^ (ar & 7);
            const int p1 = (kk * 8 + 2 * lg + 1) ^ (ar & 7);
            float4 a0 = *(const float4*)&xs[buf][ar * 64 + p0 * 4];
            float4 a1 = *(const float4*)&xs[buf][ar * 64 + p1 * 4];
            bf16x8 af;
            af[0]=f2bf(a0.x); af[1]=f2bf(a0.y); af[2]=f2bf(a0.z); af[3]=f2bf(a0.w);
            af[4]=f2bf(a1.x); af[5]=f2bf(a1.y); af[6]=f2bf(a1.z); af[7]=f2bf(a1.w);
#pragma unroll
            for (int nt = 0; nt < 6; nt++) {
                const int col = wn * 96 + nt * 16 + lr;
                const int pos = (kk * 4 + lg) ^ (col & 7);
                bf16x8 bf = *(const bf16x8*)&wsl[buf][col * 64 + pos * 8];
                acc[nt] = __builtin_amdgcn_mfma_f32_16x16x32_bf16(af, bf, acc[nt], 0, 0, 0);
            }
        }
        __syncthreads();
    }

#pragma unroll
    for (int nt = 0; nt < 6; nt++) {
#pragma unroll
        for (int r = 0; r < 4; r++) {
            const int grow = row0 + wm * 16 + lg * 4 + r;
            const int col = wn * 96 + nt * 16 + lr;
            const float val = acc[nt][r];
            if (col < 64) {
                qo[(size_t)grow * HH + col] = f2bf(val * 0.03125f);   // fold 1/sqrt(1024)
            } else if (col < 128) {
                ko[(size_t)grow * HH + (col - 64)] = f2bf(val);
            } else {
                const int b = grow >> 11, tt = grow & (TT - 1), d = col - 128;
                vt[(size_t)(b * HH + d) * VTS + tt] = f2bf(val);
            }
        }
    }
#undef STAGE
}

// ---------------- split-KV causal attention, partial accumulation ----------
// Wave-unit = (batch b, q-tile qt of 16 rows, KV chunk c of 256 keys).
// Softmax has no max subtraction (scores bounded), so partials are additive.
__global__ __launch_bounds__(256) void attn_partial(
    const unsigned short* __restrict__ q,
    const unsigned short* __restrict__ k,
    const unsigned short* __restrict__ vt,
    float* __restrict__ opart, float* __restrict__ lpart)
{
    __shared__ unsigned short Ps[4][16][72];

    const int tid = threadIdx.x;
    const int w = tid >> 6, l = tid & 63, lr = l & 15, lg = l >> 4;
    const int wu = blockIdx.x * 4 + w;

    // decode (b, qt, c) from wu
    const int b = wu / WUB;
    const int r = wu - b * WUB;
    int g = 0;
#pragma unroll
    for (int gg = 1; gg < 8; gg++) if (8 * gg * (gg + 1) <= r) g = gg;
    const int rr = r - 8 * g * (g + 1);
    const int dv = rr / (g + 1);
    const int qt = g * 16 + dv;
    const int c = rr - dv * (g + 1);

    const int qr0 = qt * 16;
    const int sbase = c * 256;
    const int ntsub = (c < g) ? 4 : ((((qt & 15) + 1) + 3) >> 2);

    const size_t qbase = ((size_t)b * TT + qr0) * HH;
    bf16x8 qf0 = *(const bf16x8*)(q + qbase + (size_t)lr * HH + lg * 8);
    bf16x8 qf1 = *(const bf16x8*)(q + qbase + (size_t)lr * HH + lg * 8 + 32);

    f32x4 o[4];
#pragma unroll
    for (int i = 0; i < 4; i++) o[i] = (f32x4){0.f, 0.f, 0.f, 0.f};
    float lsum[4] = {0.f, 0.f, 0.f, 0.f};

    const unsigned short* kg = k + (size_t)b * TT * HH;
    const unsigned short* vg = vt + (size_t)b * HH * VTS;

    for (int t = 0; t < ntsub; t++) {
        const int s0 = sbase + t * 64;
        bf16x8 kf[8], vf[8];
#pragma unroll
        for (int jt = 0; jt < 4; jt++) {
            const unsigned short* kr = kg + (size_t)(s0 + jt * 16 + lr) * HH + lg * 8;
            kf[jt * 2 + 0] = *(const bf16x8*)(kr);
            kf[jt * 2 + 1] = *(const bf16x8*)(kr + 32);
        }
#pragma unroll
        for (int dt = 0; dt < 4; dt++) {
            const unsigned short* vr = vg + (size_t)(dt * 16 + lr) * VTS + s0 + lg * 8;
            vf[dt * 2 + 0] = *(const bf16x8*)(vr);
            vf[dt * 2 + 1] = *(const bf16x8*)(vr + 32);
        }

        // QK^T -> S[16 q][64 s]
        f32x4 s[4];
#pragma unroll
        for (int jt = 0; jt < 4; jt++) {
            f32x4 a = (f32x4){0.f, 0.f, 0.f, 0.f};
            a = __builtin_amdgcn_mfma_f32_16x16x32_bf16(qf0, kf[jt * 2 + 0], a, 0, 0, 0);
            a = __builtin_amdgcn_mfma_f32_16x16x32_bf16(qf1, kf[jt * 2 + 1], a, 0, 0, 0);
            s[jt] = a;
        }

        // exp + causal mask (mask if tile's max key > tile's MIN query row)
        float rsum[4] = {0.f, 0.f, 0.f, 0.f};
        const bool masked = (s0 + 63 > qr0);
#pragma unroll
        for (int jt = 0; jt < 4; jt++) {
            const int scol = s0 + jt * 16 + lr;
#pragma unroll
            for (int rI = 0; rI < 4; rI++) {
                const int grow = qr0 + lg * 4 + rI;
                float p = __expf(s[jt][rI]);
                if (masked && scol > grow) p = 0.f;
                rsum[rI] += p;
                Ps[w][lg * 4 + rI][jt * 16 + lr] = f2bf(p);
            }
        }
#pragma unroll
        for (int rI = 0; rI < 4; rI++) {
            float v = rsum[rI];
            v += __shfl_xor(v, 1);
            v += __shfl_xor(v, 2);
            v += __shfl_xor(v, 4);
            v += __shfl_xor(v, 8);
            lsum[rI] += v;
        }

        // PV
#pragma unroll
        for (int ks = 0; ks < 2; ks++) {
            bf16x8 pf = *(const bf16x8*)&Ps[w][lr][ks * 32 + lg * 8];
#pragma unroll
            for (int dt = 0; dt < 4; dt++)
                o[dt] = __builtin_amdgcn_mfma_f32_16x16x32_bf16(pf, vf[dt * 2 + ks], o[dt], 0, 0, 0);
        }
    }

    // flush partials (coalesced: 16 lanes lr -> 16 consecutive floats)
#pragma unroll
    for (int dt = 0; dt < 4; dt++)
#pragma unroll
        for (int rI = 0; rI < 4; rI++)
            opart[((size_t)wu * 16 + lg * 4 + rI) * 64 + dt * 16 + lr] = o[dt][rI];
    if (lr == 0) {
#pragma unroll
        for (int rI = 0; rI < 4; rI++)
            lpart[wu * 16 + lg * 4 + rI] = lsum[rI];
    }
}

// ---------------- partial reduction + normalize ----------------
__global__ __launch_bounds__(256) void attn_reduce(
    const float* __restrict__ opart, const float* __restrict__ lpart,
    float* __restrict__ out)
{
    const int bx = blockIdx.x;            // 0..1023
    const int b = bx >> 7, qt = bx & 127;
    const int g = qt >> 4;
    const int base = b * WUB + 8 * g * (g + 1) + (qt - g * 16) * (g + 1);
    const int nch = g + 1;
    const int tid = threadIdx.x;
    const int row = tid >> 4;
    const int d4 = (tid & 15) * 4;

    float4 acc = {0.f, 0.f, 0.f, 0.f};
    float ls = 0.f;
    for (int ch = 0; ch < nch; ch++) {
        const float* op = opart + ((size_t)(base + ch) * 16 + row) * 64 + d4;
        float4 v = *(const float4*)op;
        acc.x += v.x; acc.y += v.y; acc.z += v.z; acc.w += v.w;
        ls += lpart[(base + ch) * 16 + row];
    }
    const float inv = 1.f / ls;
    float4 res = {acc.x * inv, acc.y * inv, acc.z * inv, acc.w * inv};
    *(float4*)(out + ((size_t)b * TT + qt * 16 + row) * 64 + d4) = res;
}

extern "C" void kernel_launch(void* const* d_in, const int* in_sizes, int n_in,
                              void* d_out, int out_size, void* d_ws, size_t ws_size,
                              hipStream_t stream) {
    const float* x  = (const float*)d_in[0];
    const float* Wq = (const float*)d_in[1];
    const float* Wk = (const float*)d_in[2];
    const float* Wv = (const float*)d_in[3];
    float* out = (float*)d_out;

    unsigned short* wbf = (unsigned short*)d_ws;                 // 384 KB
    unsigned short* qws = wbf + (size_t)192 * CC;                // 2 MB
    unsigned short* kws = qws + (size_t)BB * TT * HH;            // 2 MB
    unsigned short* vws = kws + (size_t)BB * TT * HH;            // 2.16 MB (padded V^T)
    float* opart = (float*)(vws + (size_t)BB * HH * VTS);        // 18.9 MB
    float* lpart = opart + (size_t)NWU * 16 * 64;                // 295 KB

    wconv<<<dim3(96), dim3(256), 0, stream>>>(Wq, Wk, Wv, wbf);
    qkv_proj<<<dim3(256), dim3(512), 0, stream>>>(x, wbf, qws, kws, vws);
    attn_partial<<<dim3(NWU / 4), dim3(256), 0, stream>>>(qws, kws, vws, opart, lpart);
    attn_reduce<<<dim3(BB * 128), dim3(256), 0, stream>>>(opart, lpart, out);
}

// Round 8
// 77.002 us; speedup vs baseline: 1.1570x; 1.1570x over previous
//
#include <hip/hip_runtime.h>
#include <hip/hip_bf16.h>
#include <math.h>

#define BB 8
#define TT 2048
#define CC 1024
#define HH 64
#define VTS 2112         // padded V^T row stride
#define WUB 576          // wave-units per batch = sum over qtiles of (qt/16 + 1)
#define NWU (BB * WUB)   // 4608 total wave-units

typedef __attribute__((ext_vector_type(8))) short bf16x8;
typedef __attribute__((ext_vector_type(4))) float f32x4;
typedef __attribute__((ext_vector_type(8))) unsigned short us8;

__device__ __forceinline__ unsigned short f2bf(float f) {
    return __builtin_bit_cast(unsigned short, __float2bfloat16(f));
}

#define GLOAD_LDS16(g, l) \
    __builtin_amdgcn_global_load_lds( \
        (const __attribute__((address_space(1))) void*)(g), \
        (__attribute__((address_space(3))) void*)(l), 16, 0, 0)

// ---------------- W fp32 -> bf16 pre-convert ----------------
__global__ __launch_bounds__(256) void wconv(
    const float* __restrict__ Wq, const float* __restrict__ Wk,
    const float* __restrict__ Wv, unsigned short* __restrict__ wbf)
{
    const int i = blockIdx.x * 256 + threadIdx.x;     // 8-elem group id
    const float* srcs[3] = {Wq, Wk, Wv};
    const float* src = srcs[i >> 13] + (size_t)(i & 8191) * 8;
    float4 a = *(const float4*)(src);
    float4 b = *(const float4*)(src + 4);
    us8 u;
    u[0]=f2bf(a.x); u[1]=f2bf(a.y); u[2]=f2bf(a.z); u[3]=f2bf(a.w);
    u[4]=f2bf(b.x); u[5]=f2bf(b.y); u[6]=f2bf(b.z); u[7]=f2bf(b.w);
    *(us8*)(wbf + (size_t)i * 8) = u;
}

// ---------------- QKV projection: LDS double-buffered MFMA GEMM ----------
__global__ __launch_bounds__(512) void qkv_proj(
    const float* __restrict__ x,
    const unsigned short* __restrict__ wbf,
    unsigned short* __restrict__ qo,
    unsigned short* __restrict__ ko,
    unsigned short* __restrict__ vt)
{
    __shared__ float xs[2][64 * 64];            // [buf][row(64)][k(64 fp32)]
    __shared__ unsigned short wsl[2][192 * 64]; // [buf][col(192)][k(64 bf16)]

    const int tid = threadIdx.x;
    const int w = tid >> 6, l = tid & 63, lr = l & 15, lg = l >> 4;
    const int wm = w >> 1, wn = w & 1;
    const int row0 = blockIdx.x * 64;

    f32x4 acc[6];
#pragma unroll
    for (int i = 0; i < 6; i++) acc[i] = (f32x4){0.f, 0.f, 0.f, 0.f};

#define STAGE(buf, t)                                                          \
    {                                                                          \
        const int k0 = (t) * 64;                                               \
        _Pragma("unroll")                                                      \
        for (int i = 0; i < 2; i++) {                                          \
            const int ci = w * 128 + i * 64 + l;       /* 0..1023 */           \
            const int r = ci >> 4, c = ci & 15;                                \
            const float* g = x + (size_t)(row0 + r) * CC + k0 +                \
                             ((c ^ (r & 7)) << 2);                             \
            GLOAD_LDS16(g, &xs[buf][ci * 4]);                                  \
        }                                                                      \
        _Pragma("unroll")                                                      \
        for (int i = 0; i < 3; i++) {                                          \
            const int ci = w * 192 + i * 64 + l;       /* 0..1535 */           \
            const int r = ci >> 3, c = ci & 7;                                 \
            const unsigned short* g = wbf + (size_t)r * CC + k0 +              \
                                      ((c ^ (r & 7)) << 3);                    \
            GLOAD_LDS16(g, &wsl[buf][ci * 8]);                                 \
        }                                                                      \
    }

    STAGE(0, 0);
    __syncthreads();

    for (int t = 0; t < 16; t++) {
        const int buf = t & 1;
        if (t < 15) STAGE(buf ^ 1, t + 1);

        const int ar = wm * 16 + lr;
#pragma unroll
        for (int kk = 0; kk < 2; kk++) {
            const int p0 = (kk * 8 + 2 * lg) ^ (ar & 7);
            const int p1 = (kk * 8 + 2 * lg + 1) ^ (ar & 7);
            float4 a0 = *(const float4*)&xs[buf][ar * 64 + p0 * 4];
            float4 a1 = *(const float4*)&xs[buf][ar * 64 + p1 * 4];
            bf16x8 af;
            af[0]=f2bf(a0.x); af[1]=f2bf(a0.y); af[2]=f2bf(a0.z); af[3]=f2bf(a0.w);
            af[4]=f2bf(a1.x); af[5]=f2bf(a1.y); af[6]=f2bf(a1.z); af[7]=f2bf(a1.w);
#pragma unroll
            for (int nt = 0; nt < 6; nt++) {
                const int col = wn * 96 + nt * 16 + lr;
                const int pos = (kk * 4 + lg) ^ (col & 7);
                bf16x8 bf = *(const bf16x8*)&wsl[buf][col * 64 + pos * 8];
                acc[nt] = __builtin_amdgcn_mfma_f32_16x16x32_bf16(af, bf, acc[nt], 0, 0, 0);
            }
        }
        __syncthreads();
    }

#pragma unroll
    for (int nt = 0; nt < 6; nt++) {
#pragma unroll
        for (int r = 0; r < 4; r++) {
            const int grow = row0 + wm * 16 + lg * 4 + r;
            const int col = wn * 96 + nt * 16 + lr;
            const float val = acc[nt][r];
            if (col < 64) {
                qo[(size_t)grow * HH + col] = f2bf(val * 0.03125f);   // fold 1/sqrt(1024)
            } else if (col < 128) {
                ko[(size_t)grow * HH + (col - 64)] = f2bf(val);
            } else {
                const int b = grow >> 11, tt = grow & (TT - 1), d = col - 128;
                vt[(size_t)(b * HH + d) * VTS + tt] = f2bf(val);
            }
        }
    }
#undef STAGE
}

// ---------------- split-KV causal attention, partial accumulation ----------
// __launch_bounds__(256, 4): VGPR cap 128 so kf[8]+vf[8] (64 VGPRs) stay
// live and all 16 global loads issue back-to-back (round-7 post-mortem:
// VGPR=56 made parallel loads impossible -> serialized memory chain).
__global__ __launch_bounds__(256, 4) void attn_partial(
    const unsigned short* __restrict__ q,
    const unsigned short* __restrict__ k,
    const unsigned short* __restrict__ vt,
    float* __restrict__ opart, float* __restrict__ lpart)
{
    __shared__ unsigned short Ps[4][16][72];

    const int tid = threadIdx.x;
    const int w = tid >> 6, l = tid & 63, lr = l & 15, lg = l >> 4;
    const int wu = blockIdx.x * 4 + w;

    // decode (b, qt, c) from wu
    const int b = wu / WUB;
    const int r = wu - b * WUB;
    int g = 0;
#pragma unroll
    for (int gg = 1; gg < 8; gg++) if (8 * gg * (gg + 1) <= r) g = gg;
    const int rr = r - 8 * g * (g + 1);
    const int dv = rr / (g + 1);
    const int qt = g * 16 + dv;
    const int c = rr - dv * (g + 1);

    const int qr0 = qt * 16;
    const int sbase = c * 256;
    const int ntsub = (c < g) ? 4 : ((((qt & 15) + 1) + 3) >> 2);

    const size_t qbase = ((size_t)b * TT + qr0) * HH;
    bf16x8 qf0 = *(const bf16x8*)(q + qbase + (size_t)lr * HH + lg * 8);
    bf16x8 qf1 = *(const bf16x8*)(q + qbase + (size_t)lr * HH + lg * 8 + 32);

    f32x4 o[4];
#pragma unroll
    for (int i = 0; i < 4; i++) o[i] = (f32x4){0.f, 0.f, 0.f, 0.f};
    float lsum[4] = {0.f, 0.f, 0.f, 0.f};

    const unsigned short* kg = k + (size_t)b * TT * HH;
    const unsigned short* vg = vt + (size_t)b * HH * VTS;

    for (int t = 0; t < ntsub; t++) {
        const int s0 = sbase + t * 64;
        bf16x8 kf[8], vf[8];
#pragma unroll
        for (int jt = 0; jt < 4; jt++) {
            const unsigned short* kr = kg + (size_t)(s0 + jt * 16 + lr) * HH + lg * 8;
            kf[jt * 2 + 0] = *(const bf16x8*)(kr);
            kf[jt * 2 + 1] = *(const bf16x8*)(kr + 32);
        }
#pragma unroll
        for (int dt = 0; dt < 4; dt++) {
            const unsigned short* vr = vg + (size_t)(dt * 16 + lr) * VTS + s0 + lg * 8;
            vf[dt * 2 + 0] = *(const bf16x8*)(vr);
            vf[dt * 2 + 1] = *(const bf16x8*)(vr + 32);
        }

        // QK^T -> S[16 q][64 s]
        f32x4 s[4];
#pragma unroll
        for (int jt = 0; jt < 4; jt++) {
            f32x4 a = (f32x4){0.f, 0.f, 0.f, 0.f};
            a = __builtin_amdgcn_mfma_f32_16x16x32_bf16(qf0, kf[jt * 2 + 0], a, 0, 0, 0);
            a = __builtin_amdgcn_mfma_f32_16x16x32_bf16(qf1, kf[jt * 2 + 1], a, 0, 0, 0);
            s[jt] = a;
        }

        // exp + causal mask (mask if tile's max key > tile's MIN query row)
        float rsum[4] = {0.f, 0.f, 0.f, 0.f};
        const bool masked = (s0 + 63 > qr0);
#pragma unroll
        for (int jt = 0; jt < 4; jt++) {
            const int scol = s0 + jt * 16 + lr;
#pragma unroll
            for (int rI = 0; rI < 4; rI++) {
                const int grow = qr0 + lg * 4 + rI;
                float p = __expf(s[jt][rI]);
                if (masked && scol > grow) p = 0.f;
                rsum[rI] += p;
                Ps[w][lg * 4 + rI][jt * 16 + lr] = f2bf(p);
            }
        }
#pragma unroll
        for (int rI = 0; rI < 4; rI++) {
            float v = rsum[rI];
            v += __shfl_xor(v, 1);
            v += __shfl_xor(v, 2);
            v += __shfl_xor(v, 4);
            v += __shfl_xor(v, 8);
            lsum[rI] += v;
        }

        // PV
#pragma unroll
        for (int ks = 0; ks < 2; ks++) {
            bf16x8 pf = *(const bf16x8*)&Ps[w][lr][ks * 32 + lg * 8];
#pragma unroll
            for (int dt = 0; dt < 4; dt++)
                o[dt] = __builtin_amdgcn_mfma_f32_16x16x32_bf16(pf, vf[dt * 2 + ks], o[dt], 0, 0, 0);
        }
    }

    // flush partials (coalesced: 16 lanes lr -> 16 consecutive floats)
#pragma unroll
    for (int dt = 0; dt < 4; dt++)
#pragma unroll
        for (int rI = 0; rI < 4; rI++)
            opart[((size_t)wu * 16 + lg * 4 + rI) * 64 + dt * 16 + lr] = o[dt][rI];
    if (lr == 0) {
#pragma unroll
        for (int rI = 0; rI < 4; rI++)
            lpart[wu * 16 + lg * 4 + rI] = lsum[rI];
    }
}

// ---------------- partial reduction + normalize ----------------
__global__ __launch_bounds__(256) void attn_reduce(
    const float* __restrict__ opart, const float* __restrict__ lpart,
    float* __restrict__ out)
{
    const int bx = blockIdx.x;            // 0..1023
    const int b = bx >> 7, qt = bx & 127;
    const int g = qt >> 4;
    const int base = b * WUB + 8 * g * (g + 1) + (qt - g * 16) * (g + 1);
    const int nch = g + 1;
    const int tid = threadIdx.x;
    const int row = tid >> 4;
    const int d4 = (tid & 15) * 4;

    float4 acc = {0.f, 0.f, 0.f, 0.f};
    float ls = 0.f;
    for (int ch = 0; ch < nch; ch++) {
        const float* op = opart + ((size_t)(base + ch) * 16 + row) * 64 + d4;
        float4 v = *(const float4*)op;
        acc.x += v.x; acc.y += v.y; acc.z += v.z; acc.w += v.w;
        ls += lpart[(base + ch) * 16 + row];
    }
    const float inv = 1.f / ls;
    float4 res = {acc.x * inv, acc.y * inv, acc.z * inv, acc.w * inv};
    *(float4*)(out + ((size_t)b * TT + qt * 16 + row) * 64 + d4) = res;
}

extern "C" void kernel_launch(void* const* d_in, const int* in_sizes, int n_in,
                              void* d_out, int out_size, void* d_ws, size_t ws_size,
                              hipStream_t stream) {
    const float* x  = (const float*)d_in[0];
    const float* Wq = (const float*)d_in[1];
    const float* Wk = (const float*)d_in[2];
    const float* Wv = (const float*)d_in[3];
    float* out = (float*)d_out;

    unsigned short* wbf = (unsigned short*)d_ws;                 // 384 KB
    unsigned short* qws = wbf + (size_t)192 * CC;                // 2 MB
    unsigned short* kws = qws + (size_t)BB * TT * HH;            // 2 MB
    unsigned short* vws = kws + (size_t)BB * TT * HH;            // 2.16 MB (padded V^T)
    float* opart = (float*)(vws + (size_t)BB * HH * VTS);        // 18.9 MB
    float* lpart = opart + (size_t)NWU * 16 * 64;                // 295 KB

    wconv<<<dim3(96), dim3(256), 0, stream>>>(Wq, Wk, Wv, wbf);
    qkv_proj<<<dim3(256), dim3(512), 0, stream>>>(x, wbf, qws, kws, vws);
    attn_partial<<<dim3(NWU / 4), dim3(256), 0, stream>>>(qws, kws, vws, opart, lpart);
    attn_reduce<<<dim3(BB * 128), dim3(256), 0, stream>>>(opart, lpart, out);
}

// Round 9
// 56.806 us; speedup vs baseline: 1.5683x; 1.3555x over previous
//
#include <hip/hip_runtime.h>
#include <hip/hip_bf16.h>
#include <math.h>

#define BB 8
#define TT 2048
#define CC 1024
#define HH 64
#define VTS 2112         // padded V^T row stride
#define WUB 576          // wave-units per batch = sum over qtiles of (qt/16 + 1)
#define NWU (BB * WUB)   // 4608 total wave-units

typedef __attribute__((ext_vector_type(8))) short bf16x8;
typedef __attribute__((ext_vector_type(4))) float f32x4;
typedef __attribute__((ext_vector_type(8))) unsigned short us8;

__device__ __forceinline__ unsigned short f2bf(float f) {
    return __builtin_bit_cast(unsigned short, __float2bfloat16(f));
}

#define GLOAD_LDS16(g, l) \
    __builtin_amdgcn_global_load_lds( \
        (const __attribute__((address_space(1))) void*)(g), \
        (__attribute__((address_space(3))) void*)(l), 16, 0, 0)

// ---------------- W fp32 -> bf16 pre-convert ----------------
__global__ __launch_bounds__(256) void wconv(
    const float* __restrict__ Wq, const float* __restrict__ Wk,
    const float* __restrict__ Wv, unsigned short* __restrict__ wbf)
{
    const int i = blockIdx.x * 256 + threadIdx.x;     // 8-elem group id
    const float* srcs[3] = {Wq, Wk, Wv};
    const float* src = srcs[i >> 13] + (size_t)(i & 8191) * 8;
    float4 a = *(const float4*)(src);
    float4 b = *(const float4*)(src + 4);
    us8 u;
    u[0]=f2bf(a.x); u[1]=f2bf(a.y); u[2]=f2bf(a.z); u[3]=f2bf(a.w);
    u[4]=f2bf(b.x); u[5]=f2bf(b.y); u[6]=f2bf(b.z); u[7]=f2bf(b.w);
    *(us8*)(wbf + (size_t)i * 8) = u;
}

// ---------------- QKV projection: LDS double-buffered MFMA GEMM ----------
__global__ __launch_bounds__(512) void qkv_proj(
    const float* __restrict__ x,
    const unsigned short* __restrict__ wbf,
    unsigned short* __restrict__ qo,
    unsigned short* __restrict__ ko,
    unsigned short* __restrict__ vt)
{
    __shared__ float xs[2][64 * 64];            // [buf][row(64)][k(64 fp32)]
    __shared__ unsigned short wsl[2][192 * 64]; // [buf][col(192)][k(64 bf16)]

    const int tid = threadIdx.x;
    const int w = tid >> 6, l = tid & 63, lr = l & 15, lg = l >> 4;
    const int wm = w >> 1, wn = w & 1;
    const int row0 = blockIdx.x * 64;

    f32x4 acc[6];
#pragma unroll
    for (int i = 0; i < 6; i++) acc[i] = (f32x4){0.f, 0.f, 0.f, 0.f};

#define STAGE(buf, t)                                                          \
    {                                                                          \
        const int k0 = (t) * 64;                                               \
        _Pragma("unroll")                                                      \
        for (int i = 0; i < 2; i++) {                                          \
            const int ci = w * 128 + i * 64 + l;       /* 0..1023 */           \
            const int r = ci >> 4, c = ci & 15;                                \
            const float* g = x + (size_t)(row0 + r) * CC + k0 +                \
                             ((c ^ (r & 7)) << 2);                             \
            GLOAD_LDS16(g, &xs[buf][ci * 4]);                                  \
        }                                                                      \
        _Pragma("unroll")                                                      \
        for (int i = 0; i < 3; i++) {                                          \
            const int ci = w * 192 + i * 64 + l;       /* 0..1535 */           \
            const int r = ci >> 3, c = ci & 7;                                 \
            const unsigned short* g = wbf + (size_t)r * CC + k0 +              \
                                      ((c ^ (r & 7)) << 3);                    \
            GLOAD_LDS16(g, &wsl[buf][ci * 8]);                                 \
        }                                                                      \
    }

    STAGE(0, 0);
    __syncthreads();

    for (int t = 0; t < 16; t++) {
        const int buf = t & 1;
        if (t < 15) STAGE(buf ^ 1, t + 1);

        const int ar = wm * 16 + lr;
#pragma unroll
        for (int kk = 0; kk < 2; kk++) {
            const int p0 = (kk * 8 + 2 * lg) ^ (ar & 7);
            const int p1 = (kk * 8 + 2 * lg + 1) ^ (ar & 7);
            float4 a0 = *(const float4*)&xs[buf][ar * 64 + p0 * 4];
            float4 a1 = *(const float4*)&xs[buf][ar * 64 + p1 * 4];
            bf16x8 af;
            af[0]=f2bf(a0.x); af[1]=f2bf(a0.y); af[2]=f2bf(a0.z); af[3]=f2bf(a0.w);
            af[4]=f2bf(a1.x); af[5]=f2bf(a1.y); af[6]=f2bf(a1.z); af[7]=f2bf(a1.w);
#pragma unroll
            for (int nt = 0; nt < 6; nt++) {
                const int col = wn * 96 + nt * 16 + lr;
                const int pos = (kk * 4 + lg) ^ (col & 7);
                bf16x8 bf = *(const bf16x8*)&wsl[buf][col * 64 + pos * 8];
                acc[nt] = __builtin_amdgcn_mfma_f32_16x16x32_bf16(af, bf, acc[nt], 0, 0, 0);
            }
        }
        __syncthreads();
    }

#pragma unroll
    for (int nt = 0; nt < 6; nt++) {
#pragma unroll
        for (int r = 0; r < 4; r++) {
            const int grow = row0 + wm * 16 + lg * 4 + r;
            const int col = wn * 96 + nt * 16 + lr;
            const float val = acc[nt][r];
            if (col < 64) {
                qo[(size_t)grow * HH + col] = f2bf(val * 0.03125f);   // fold 1/sqrt(1024)
            } else if (col < 128) {
                ko[(size_t)grow * HH + (col - 64)] = f2bf(val);
            } else {
                const int b = grow >> 11, tt = grow & (TT - 1), d = col - 128;
                vt[(size_t)(b * HH + d) * VTS + tt] = f2bf(val);
            }
        }
    }
#undef STAGE
}

// ---------------- split-KV causal attention, cooperative-block version ----
// Block = (batch b, q-group G of 4 q-tiles, 256-key chunk c), 4 waves.
// The block stages its K/V chunk into LDS ONCE via global_load_lds (no VGPR
// payload, async), double-buffered in 64-key subtiles; each wave consumes
// the SAME staged subtile against its own q-tile (qt = 4G + w). Round-8
// post-mortem: per-wave global gathers were serializing at ~6000 cy/subtile;
// LDS staging amortizes the traffic 4x and removes the register bottleneck.
__global__ __launch_bounds__(256, 3) void attn_partial(
    const unsigned short* __restrict__ q,
    const unsigned short* __restrict__ k,
    const unsigned short* __restrict__ vt,
    float* __restrict__ opart, float* __restrict__ lpart)
{
    __shared__ unsigned short Ks[2][64 * 64];   // [buf][row(64)][k(64)] 8KB/buf
    __shared__ unsigned short Vs[2][64 * 64];   // [buf][d(64)][s(64)]  8KB/buf
    __shared__ unsigned short Ps[4][16][72];

    const int tid = threadIdx.x;
    const int w = tid >> 6, l = tid & 63, lr = l & 15, lg = l >> 4;

    // decode block -> (b, quad a, d, c); G = 4a+d, qt = 4G+w
    const int bid = blockIdx.x;
    const int b = bid / 144;
    const int r = bid - b * 144;
    int a = 0;
#pragma unroll
    for (int aa = 1; aa < 8; aa++) if (2 * aa * (aa + 1) <= r) a = aa;
    const int rr = r - 2 * a * (a + 1);
    const int d = rr / (a + 1);
    const int c = rr - d * (a + 1);
    const int G = 4 * a + d;
    const int qt = 4 * G + w;
    const int qr0 = qt * 16;
    const int nstage = (c == a) ? (d + 1) : 4;   // uniform across waves
    const int sbase = c * 256;
    // opart slot (same mapping as before; g = qt>>4 == a)
    const int wu = b * WUB + 8 * a * (a + 1) + (qt & 15) * (a + 1) + c;

    const size_t qbase = ((size_t)b * TT + qr0) * HH;
    bf16x8 qf0 = *(const bf16x8*)(q + qbase + (size_t)lr * HH + lg * 8);
    bf16x8 qf1 = *(const bf16x8*)(q + qbase + (size_t)lr * HH + lg * 8 + 32);

    const unsigned short* kg = k + (size_t)b * TT * HH;
    const unsigned short* vg = vt + (size_t)b * HH * VTS;

    f32x4 o[4];
#pragma unroll
    for (int i = 0; i < 4; i++) o[i] = (f32x4){0.f, 0.f, 0.f, 0.f};
    float lsum[4] = {0.f, 0.f, 0.f, 0.f};

    // stage subtile t: 64 keys of K (64x64 bf16) + V^T (64d x 64s).
    // Linear LDS dest + inverse-swizzled global source (chunk cc^(row&7));
    // readers swizzle, so net conflict-free (rule 21).
#define ASTAGE(buf, t)                                                         \
    {                                                                          \
        const int s0_ = sbase + (t) * 64;                                      \
        _Pragma("unroll")                                                      \
        for (int i = 0; i < 2; i++) {                                          \
            const int ci = i * 256 + tid;            /* 0..511 */              \
            const int rK = ci >> 3, cc = ci & 7;                               \
            GLOAD_LDS16(kg + (size_t)(s0_ + rK) * HH + ((cc ^ (rK & 7)) << 3), \
                        &Ks[buf][ci * 8]);                                     \
        }                                                                      \
        _Pragma("unroll")                                                      \
        for (int i = 0; i < 2; i++) {                                          \
            const int ci = i * 256 + tid;                                      \
            const int rV = ci >> 3, cc = ci & 7;                               \
            GLOAD_LDS16(vg + (size_t)rV * VTS + s0_ + ((cc ^ (rV & 7)) << 3),  \
                        &Vs[buf][ci * 8]);                                     \
        }                                                                      \
    }

    ASTAGE(0, 0);
    __syncthreads();   // drains vmcnt -> buf0 ready

    for (int t = 0; t < nstage; t++) {
        const int buf = t & 1;
        if (t + 1 < nstage) ASTAGE(buf ^ 1, t + 1);   // async prefetch
        const int s0 = sbase + t * 64;

        // QK^T -> S[16 q][64 s] (K frags from LDS, swizzled)
        f32x4 s[4];
#pragma unroll
        for (int jt = 0; jt < 4; jt++) {
            const int row = jt * 16 + lr;
            bf16x8 kf0 = *(const bf16x8*)&Ks[buf][row * 64 + ((lg ^ (row & 7)) << 3)];
            bf16x8 kf1 = *(const bf16x8*)&Ks[buf][row * 64 + (((lg + 4) ^ (row & 7)) << 3)];
            f32x4 acc = (f32x4){0.f, 0.f, 0.f, 0.f};
            acc = __builtin_amdgcn_mfma_f32_16x16x32_bf16(qf0, kf0, acc, 0, 0, 0);
            acc = __builtin_amdgcn_mfma_f32_16x16x32_bf16(qf1, kf1, acc, 0, 0, 0);
            s[jt] = acc;
        }

        // exp + causal mask (mask iff tile's max key > tile's MIN query row)
        float rsum[4] = {0.f, 0.f, 0.f, 0.f};
        const bool masked = (s0 + 63 > qr0);
#pragma unroll
        for (int jt = 0; jt < 4; jt++) {
            const int scol = s0 + jt * 16 + lr;
#pragma unroll
            for (int rI = 0; rI < 4; rI++) {
                const int grow = qr0 + lg * 4 + rI;
                float p = __expf(s[jt][rI]);
                if (masked && scol > grow) p = 0.f;
                rsum[rI] += p;
                Ps[w][lg * 4 + rI][jt * 16 + lr] = f2bf(p);
            }
        }
#pragma unroll
        for (int rI = 0; rI < 4; rI++) {
            float v = rsum[rI];
            v += __shfl_xor(v, 1);
            v += __shfl_xor(v, 2);
            v += __shfl_xor(v, 4);
            v += __shfl_xor(v, 8);
            lsum[rI] += v;
        }

        // PV: O[16][64] += P[16][64] x V^T (V frags from LDS, swizzled)
#pragma unroll
        for (int ks = 0; ks < 2; ks++) {
            bf16x8 pf = *(const bf16x8*)&Ps[w][lr][ks * 32 + lg * 8];
#pragma unroll
            for (int dt = 0; dt < 4; dt++) {
                const int dd = dt * 16 + lr;
                bf16x8 vf = *(const bf16x8*)&Vs[buf][dd * 64 + (((lg + 4 * ks) ^ (dd & 7)) << 3)];
                o[dt] = __builtin_amdgcn_mfma_f32_16x16x32_bf16(pf, vf, o[dt], 0, 0, 0);
            }
        }
        __syncthreads();   // prefetch landed + all waves done with buf
    }
#undef ASTAGE

    // flush partials (coalesced: 16 lanes lr -> 16 consecutive floats)
#pragma unroll
    for (int dt = 0; dt < 4; dt++)
#pragma unroll
        for (int rI = 0; rI < 4; rI++)
            opart[((size_t)wu * 16 + lg * 4 + rI) * 64 + dt * 16 + lr] = o[dt][rI];
    if (lr == 0) {
#pragma unroll
        for (int rI = 0; rI < 4; rI++)
            lpart[wu * 16 + lg * 4 + rI] = lsum[rI];
    }
}

// ---------------- partial reduction + normalize ----------------
__global__ __launch_bounds__(256) void attn_reduce(
    const float* __restrict__ opart, const float* __restrict__ lpart,
    float* __restrict__ out)
{
    const int bx = blockIdx.x;            // 0..1023
    const int b = bx >> 7, qt = bx & 127;
    const int g = qt >> 4;
    const int base = b * WUB + 8 * g * (g + 1) + (qt - g * 16) * (g + 1);
    const int nch = g + 1;
    const int tid = threadIdx.x;
    const int row = tid >> 4;
    const int d4 = (tid & 15) * 4;

    float4 acc = {0.f, 0.f, 0.f, 0.f};
    float ls = 0.f;
    for (int ch = 0; ch < nch; ch++) {
        const float* op = opart + ((size_t)(base + ch) * 16 + row) * 64 + d4;
        float4 v = *(const float4*)op;
        acc.x += v.x; acc.y += v.y; acc.z += v.z; acc.w += v.w;
        ls += lpart[(base + ch) * 16 + row];
    }
    const float inv = 1.f / ls;
    float4 res = {acc.x * inv, acc.y * inv, acc.z * inv, acc.w * inv};
    *(float4*)(out + ((size_t)b * TT + qt * 16 + row) * 64 + d4) = res;
}

extern "C" void kernel_launch(void* const* d_in, const int* in_sizes, int n_in,
                              void* d_out, int out_size, void* d_ws, size_t ws_size,
                              hipStream_t stream) {
    const float* x  = (const float*)d_in[0];
    const float* Wq = (const float*)d_in[1];
    const float* Wk = (const float*)d_in[2];
    const float* Wv = (const float*)d_in[3];
    float* out = (float*)d_out;

    unsigned short* wbf = (unsigned short*)d_ws;                 // 384 KB
    unsigned short* qws = wbf + (size_t)192 * CC;                // 2 MB
    unsigned short* kws = qws + (size_t)BB * TT * HH;            // 2 MB
    unsigned short* vws = kws + (size_t)BB * TT * HH;            // 2.16 MB (padded V^T)
    float* opart = (float*)(vws + (size_t)BB * HH * VTS);       // 18.9 MB
    float* lpart = opart + (size_t)NWU * 16 * 64;                // 295 KB

    wconv<<<dim3(96), dim3(256), 0, stream>>>(Wq, Wk, Wv, wbf);
    qkv_proj<<<dim3(256), dim3(512), 0, stream>>>(x, wbf, qws, kws, vws);
    attn_partial<<<dim3(BB * 144), dim3(256), 0, stream>>>(qws, kws, vws, opart, lpart);
    attn_reduce<<<dim3(BB * 128), dim3(256), 0, stream>>>(opart, lpart, out);
}

// Round 10
// 53.290 us; speedup vs baseline: 1.6718x; 1.0660x over previous
//
#include <hip/hip_runtime.h>
#include <hip/hip_bf16.h>
#include <math.h>

#define BB 8
#define TT 2048
#define CC 1024
#define HH 64
#define VTS 2112         // padded V^T row stride
#define WUB 576          // wave-units per batch = sum over qtiles of (qt/16 + 1)
#define NWU (BB * WUB)   // 4608 total wave-units
#define QSCALE 0.0450842200f   // (1/32) * log2(e): softmax uses exp2

typedef __attribute__((ext_vector_type(8))) short bf16x8;
typedef __attribute__((ext_vector_type(4))) float f32x4;
typedef __attribute__((ext_vector_type(8))) unsigned short us8;
typedef __attribute__((ext_vector_type(4))) unsigned short us4;

__device__ __forceinline__ unsigned short f2bf(float f) {
    return __builtin_bit_cast(unsigned short, __float2bfloat16(f));
}
__device__ __forceinline__ float bf2f(unsigned short u) {
    union { unsigned int i; float f; } x; x.i = ((unsigned int)u) << 16; return x.f;
}

#define GLOAD_LDS16(g, l) \
    __builtin_amdgcn_global_load_lds( \
        (const __attribute__((address_space(1))) void*)(g), \
        (__attribute__((address_space(3))) void*)(l), 16, 0, 0)

// ---------------- W fp32 -> bf16 pre-convert ----------------
__global__ __launch_bounds__(256) void wconv(
    const float* __restrict__ Wq, const float* __restrict__ Wk,
    const float* __restrict__ Wv, unsigned short* __restrict__ wbf)
{
    const int i = blockIdx.x * 256 + threadIdx.x;     // 8-elem group id
    const float* srcs[3] = {Wq, Wk, Wv};
    const float* src = srcs[i >> 13] + (size_t)(i & 8191) * 8;
    float4 a = *(const float4*)(src);
    float4 b = *(const float4*)(src + 4);
    us8 u;
    u[0]=f2bf(a.x); u[1]=f2bf(a.y); u[2]=f2bf(a.z); u[3]=f2bf(a.w);
    u[4]=f2bf(b.x); u[5]=f2bf(b.y); u[6]=f2bf(b.z); u[7]=f2bf(b.w);
    *(us8*)(wbf + (size_t)i * 8) = u;
}

// ---------------- QKV projection: LDS double-buffered MFMA GEMM ----------
__global__ __launch_bounds__(512) void qkv_proj(
    const float* __restrict__ x,
    const unsigned short* __restrict__ wbf,
    unsigned short* __restrict__ qo,
    unsigned short* __restrict__ ko,
    unsigned short* __restrict__ vt)
{
    __shared__ float xs[2][64 * 64];            // [buf][row(64)][k(64 fp32)]
    __shared__ unsigned short wsl[2][192 * 64]; // [buf][col(192)][k(64 bf16)]

    const int tid = threadIdx.x;
    const int w = tid >> 6, l = tid & 63, lr = l & 15, lg = l >> 4;
    const int wm = w >> 1, wn = w & 1;
    const int row0 = blockIdx.x * 64;

    f32x4 acc[6];
#pragma unroll
    for (int i = 0; i < 6; i++) acc[i] = (f32x4){0.f, 0.f, 0.f, 0.f};

#define STAGE(buf, t)                                                          \
    {                                                                          \
        const int k0 = (t) * 64;                                               \
        _Pragma("unroll")                                                      \
        for (int i = 0; i < 2; i++) {                                          \
            const int ci = w * 128 + i * 64 + l;       /* 0..1023 */           \
            const int r = ci >> 4, c = ci & 15;                                \
            const float* g = x + (size_t)(row0 + r) * CC + k0 +                \
                             ((c ^ (r & 7)) << 2);                             \
            GLOAD_LDS16(g, &xs[buf][ci * 4]);                                  \
        }                                                                      \
        _Pragma("unroll")                                                      \
        for (int i = 0; i < 3; i++) {                                          \
            const int ci = w * 192 + i * 64 + l;       /* 0..1535 */           \
            const int r = ci >> 3, c = ci & 7;                                 \
            const unsigned short* g = wbf + (size_t)r * CC + k0 +              \
                                      ((c ^ (r & 7)) << 3);                    \
            GLOAD_LDS16(g, &wsl[buf][ci * 8]);                                 \
        }                                                                      \
    }

    STAGE(0, 0);
    __syncthreads();

    for (int t = 0; t < 16; t++) {
        const int buf = t & 1;
        if (t < 15) STAGE(buf ^ 1, t + 1);

        const int ar = wm * 16 + lr;
#pragma unroll
        for (int kk = 0; kk < 2; kk++) {
            const int p0 = (kk * 8 + 2 * lg) ^ (ar & 7);
            const int p1 = (kk * 8 + 2 * lg + 1) ^ (ar & 7);
            float4 a0 = *(const float4*)&xs[buf][ar * 64 + p0 * 4];
            float4 a1 = *(const float4*)&xs[buf][ar * 64 + p1 * 4];
            bf16x8 af;
            af[0]=f2bf(a0.x); af[1]=f2bf(a0.y); af[2]=f2bf(a0.z); af[3]=f2bf(a0.w);
            af[4]=f2bf(a1.x); af[5]=f2bf(a1.y); af[6]=f2bf(a1.z); af[7]=f2bf(a1.w);
#pragma unroll
            for (int nt = 0; nt < 6; nt++) {
                const int col = wn * 96 + nt * 16 + lr;
                const int pos = (kk * 4 + lg) ^ (col & 7);
                bf16x8 bf = *(const bf16x8*)&wsl[buf][col * 64 + pos * 8];
                acc[nt] = __builtin_amdgcn_mfma_f32_16x16x32_bf16(af, bf, acc[nt], 0, 0, 0);
            }
        }
        __syncthreads();
    }

    // q/k epilogue: direct stores (coalesced enough: 32B runs per lane group)
#pragma unroll
    for (int nt = 0; nt < 6; nt++) {
#pragma unroll
        for (int r = 0; r < 4; r++) {
            const int grow = row0 + wm * 16 + lg * 4 + r;
            const int col = wn * 96 + nt * 16 + lr;
            const float val = acc[nt][r];
            if (col < 64) {
                qo[(size_t)grow * HH + col] = f2bf(val * QSCALE);
            } else if (col < 128) {
                ko[(size_t)grow * HH + (col - 64)] = f2bf(val);
            }
        }
    }
    // V epilogue via LDS transpose (round-9 post-mortem: direct vt stores were
    // 2B scatters at 4224B lane stride -> one 64B sector per element). XOR
    // swizzle keeps both LDS phases at <=2-way conflicts.
    __syncthreads();
    unsigned short* vtile = (unsigned short*)&xs[0][0];   // reuse 8 KB of xs
    if (wn == 1) {
#pragma unroll
        for (int nt = 2; nt < 6; nt++) {
#pragma unroll
            for (int r = 0; r < 4; r++) {
                const int d = nt * 16 - 32 + lr;         // 0..63
                const int t = wm * 16 + lg * 4 + r;      // 0..63
                vtile[d * 64 + (t ^ ((d & 7) << 3))] = f2bf(acc[nt][r]);
            }
        }
    }
    __syncthreads();
    {
        const int d = tid >> 3, j = tid & 7;
        const int b = row0 >> 11, t0 = row0 & (TT - 1);
        us8 v = *(const us8*)&vtile[d * 64 + ((j * 8) ^ ((d & 7) << 3))];
        *(us8*)(vt + (size_t)(b * HH + d) * VTS + t0 + j * 8) = v;
    }
#undef STAGE
}

// ---------------- split-KV causal attention, cooperative-block version ----
// Block = (batch b, q-group G of 4 q-tiles, 256-key chunk c), 4 waves.
// K/V chunk staged once per block into LDS (global_load_lds, double-buffered
// 64-key subtiles); each wave consumes the shared subtile for its q-tile.
// lsum cross-lane reduce deferred to end (exp-sums additive across subtiles);
// softmax via exp2 (log2e folded into q scale); partials stored bf16.
__global__ __launch_bounds__(256, 3) void attn_partial(
    const unsigned short* __restrict__ q,
    const unsigned short* __restrict__ k,
    const unsigned short* __restrict__ vt,
    unsigned short* __restrict__ opart, float* __restrict__ lpart)
{
    __shared__ unsigned short Ks[2][64 * 64];
    __shared__ unsigned short Vs[2][64 * 64];
    __shared__ unsigned short Ps[4][16][72];

    const int tid = threadIdx.x;
    const int w = tid >> 6, l = tid & 63, lr = l & 15, lg = l >> 4;

    // decode block -> (b, quad a, d, c); G = 4a+d, qt = 4G+w
    const int bid = blockIdx.x;
    const int b = bid / 144;
    const int r = bid - b * 144;
    int a = 0;
#pragma unroll
    for (int aa = 1; aa < 8; aa++) if (2 * aa * (aa + 1) <= r) a = aa;
    const int rr = r - 2 * a * (a + 1);
    const int d = rr / (a + 1);
    const int c = rr - d * (a + 1);
    const int G = 4 * a + d;
    const int qt = 4 * G + w;
    const int qr0 = qt * 16;
    const int nstage = (c == a) ? (d + 1) : 4;   // uniform across waves
    const int sbase = c * 256;
    const int wu = b * WUB + 8 * a * (a + 1) + (qt & 15) * (a + 1) + c;

    const size_t qbase = ((size_t)b * TT + qr0) * HH;
    bf16x8 qf0 = *(const bf16x8*)(q + qbase + (size_t)lr * HH + lg * 8);
    bf16x8 qf1 = *(const bf16x8*)(q + qbase + (size_t)lr * HH + lg * 8 + 32);

    const unsigned short* kg = k + (size_t)b * TT * HH;
    const unsigned short* vg = vt + (size_t)b * HH * VTS;

    f32x4 o[4];
#pragma unroll
    for (int i = 0; i < 4; i++) o[i] = (f32x4){0.f, 0.f, 0.f, 0.f};
    float lacc[4] = {0.f, 0.f, 0.f, 0.f};

#define ASTAGE(buf, t)                                                         \
    {                                                                          \
        const int s0_ = sbase + (t) * 64;                                      \
        _Pragma("unroll")                                                      \
        for (int i = 0; i < 2; i++) {                                          \
            const int ci = i * 256 + tid;            /* 0..511 */              \
            const int rK = ci >> 3, cc = ci & 7;                               \
            GLOAD_LDS16(kg + (size_t)(s0_ + rK) * HH + ((cc ^ (rK & 7)) << 3), \
                        &Ks[buf][ci * 8]);                                     \
        }                                                                      \
        _Pragma("unroll")                                                      \
        for (int i = 0; i < 2; i++) {                                          \
            const int ci = i * 256 + tid;                                      \
            const int rV = ci >> 3, cc = ci & 7;                               \
            GLOAD_LDS16(vg + (size_t)rV * VTS + s0_ + ((cc ^ (rV & 7)) << 3),  \
                        &Vs[buf][ci * 8]);                                     \
        }                                                                      \
    }

    ASTAGE(0, 0);
    __syncthreads();

    for (int t = 0; t < nstage; t++) {
        const int buf = t & 1;
        if (t + 1 < nstage) ASTAGE(buf ^ 1, t + 1);
        const int s0 = sbase + t * 64;

        // QK^T -> S[16 q][64 s]
        f32x4 s[4];
#pragma unroll
        for (int jt = 0; jt < 4; jt++) {
            const int row = jt * 16 + lr;
            bf16x8 kf0 = *(const bf16x8*)&Ks[buf][row * 64 + ((lg ^ (row & 7)) << 3)];
            bf16x8 kf1 = *(const bf16x8*)&Ks[buf][row * 64 + (((lg + 4) ^ (row & 7)) << 3)];
            f32x4 acc = (f32x4){0.f, 0.f, 0.f, 0.f};
            acc = __builtin_amdgcn_mfma_f32_16x16x32_bf16(qf0, kf0, acc, 0, 0, 0);
            acc = __builtin_amdgcn_mfma_f32_16x16x32_bf16(qf1, kf1, acc, 0, 0, 0);
            s[jt] = acc;
        }

        // p = exp2(s) (log2e folded into q); causal mask; per-lane sum only
        const bool masked = (s0 + 63 > qr0);
#pragma unroll
        for (int jt = 0; jt < 4; jt++) {
            const int scol = s0 + jt * 16 + lr;
#pragma unroll
            for (int rI = 0; rI < 4; rI++) {
                const int grow = qr0 + lg * 4 + rI;
                float p = __builtin_exp2f(s[jt][rI]);
                if (masked && scol > grow) p = 0.f;
                lacc[rI] += p;
                Ps[w][lg * 4 + rI][jt * 16 + lr] = f2bf(p);
            }
        }

        // PV: O[16][64] += P[16][64] x V^T
#pragma unroll
        for (int ks = 0; ks < 2; ks++) {
            bf16x8 pf = *(const bf16x8*)&Ps[w][lr][ks * 32 + lg * 8];
#pragma unroll
            for (int dt = 0; dt < 4; dt++) {
                const int dd = dt * 16 + lr;
                bf16x8 vf = *(const bf16x8*)&Vs[buf][dd * 64 + (((lg + 4 * ks) ^ (dd & 7)) << 3)];
                o[dt] = __builtin_amdgcn_mfma_f32_16x16x32_bf16(pf, vf, o[dt], 0, 0, 0);
            }
        }
        __syncthreads();
    }
#undef ASTAGE

    // one deferred cross-lane reduce for l
    float lsum[4];
#pragma unroll
    for (int rI = 0; rI < 4; rI++) {
        float v = lacc[rI];
        v += __shfl_xor(v, 1);
        v += __shfl_xor(v, 2);
        v += __shfl_xor(v, 4);
        v += __shfl_xor(v, 8);
        lsum[rI] = v;
    }

    // flush partials (bf16; 16 lanes lr -> 32B contiguous per (dt,rI))
#pragma unroll
    for (int dt = 0; dt < 4; dt++)
#pragma unroll
        for (int rI = 0; rI < 4; rI++)
            opart[((size_t)wu * 16 + lg * 4 + rI) * 64 + dt * 16 + lr] = f2bf(o[dt][rI]);
    if (lr == 0) {
#pragma unroll
        for (int rI = 0; rI < 4; rI++)
            lpart[wu * 16 + lg * 4 + rI] = lsum[rI];
    }
}

// ---------------- partial reduction + normalize ----------------
__global__ __launch_bounds__(256) void attn_reduce(
    const unsigned short* __restrict__ opart, const float* __restrict__ lpart,
    float* __restrict__ out)
{
    const int bx = blockIdx.x;            // 0..1023
    const int b = bx >> 7, qt = bx & 127;
    const int g = qt >> 4;
    const int base = b * WUB + 8 * g * (g + 1) + (qt - g * 16) * (g + 1);
    const int nch = g + 1;
    const int tid = threadIdx.x;
    const int row = tid >> 4;
    const int d4 = (tid & 15) * 4;

    float4 acc = {0.f, 0.f, 0.f, 0.f};
    float ls = 0.f;
    for (int ch = 0; ch < nch; ch++) {
        us4 v = *(const us4*)&opart[((size_t)(base + ch) * 16 + row) * 64 + d4];
        acc.x += bf2f(v[0]); acc.y += bf2f(v[1]);
        acc.z += bf2f(v[2]); acc.w += bf2f(v[3]);
        ls += lpart[(base + ch) * 16 + row];
    }
    const float inv = 1.f / ls;
    float4 res = {acc.x * inv, acc.y * inv, acc.z * inv, acc.w * inv};
    *(float4*)(out + ((size_t)b * TT + qt * 16 + row) * 64 + d4) = res;
}

extern "C" void kernel_launch(void* const* d_in, const int* in_sizes, int n_in,
                              void* d_out, int out_size, void* d_ws, size_t ws_size,
                              hipStream_t stream) {
    const float* x  = (const float*)d_in[0];
    const float* Wq = (const float*)d_in[1];
    const float* Wk = (const float*)d_in[2];
    const float* Wv = (const float*)d_in[3];
    float* out = (float*)d_out;

    unsigned short* wbf = (unsigned short*)d_ws;                 // 384 KB
    unsigned short* qws = wbf + (size_t)192 * CC;                // 2 MB
    unsigned short* kws = qws + (size_t)BB * TT * HH;            // 2 MB
    unsigned short* vws = kws + (size_t)BB * TT * HH;            // 2.16 MB (padded V^T)
    unsigned short* opart = vws + (size_t)BB * HH * VTS;         // 9.4 MB (bf16)
    float* lpart = (float*)(opart + (size_t)NWU * 16 * 64);      // 295 KB

    wconv<<<dim3(96), dim3(256), 0, stream>>>(Wq, Wk, Wv, wbf);
    qkv_proj<<<dim3(256), dim3(512), 0, stream>>>(x, wbf, qws, kws, vws);
    attn_partial<<<dim3(BB * 144), dim3(256), 0, stream>>>(qws, kws, vws, opart, lpart);
    attn_reduce<<<dim3(BB * 128), dim3(256), 0, stream>>>(opart, lpart, out);
}

// Round 11
// 52.949 us; speedup vs baseline: 1.6826x; 1.0064x over previous
//
#include <hip/hip_runtime.h>
#include <hip/hip_bf16.h>
#include <math.h>

#define BB 8
#define TT 2048
#define CC 1024
#define HH 64
#define VTS 2112         // padded V^T row stride
#define WUB 576          // wave-units per batch = sum over qtiles of (qt/16 + 1)
#define NWU (BB * WUB)   // 4608 total wave-units
#define QSCALE 0.0450842200f   // (1/32) * log2(e): softmax uses exp2

typedef __attribute__((ext_vector_type(8))) short bf16x8;
typedef __attribute__((ext_vector_type(4))) float f32x4;
typedef __attribute__((ext_vector_type(8))) unsigned short us8;
typedef __attribute__((ext_vector_type(4))) unsigned short us4;

__device__ __forceinline__ unsigned short f2bf(float f) {
    return __builtin_bit_cast(unsigned short, __float2bfloat16(f));
}
__device__ __forceinline__ float bf2f(unsigned short u) {
    union { unsigned int i; float f; } x; x.i = ((unsigned int)u) << 16; return x.f;
}
__device__ __forceinline__ unsigned int cvtpk(float lo, float hi) {
    unsigned int r;
    asm("v_cvt_pk_bf16_f32 %0, %1, %2" : "=v"(r) : "v"(lo), "v"(hi));
    return r;
}

#define GLOAD_LDS16(g, l) \
    __builtin_amdgcn_global_load_lds( \
        (const __attribute__((address_space(1))) void*)(g), \
        (__attribute__((address_space(3))) void*)(l), 16, 0, 0)

// ---------------- W fp32 -> bf16 pre-convert ----------------
__global__ __launch_bounds__(256) void wconv(
    const float* __restrict__ Wq, const float* __restrict__ Wk,
    const float* __restrict__ Wv, unsigned short* __restrict__ wbf)
{
    const int i = blockIdx.x * 256 + threadIdx.x;     // 8-elem group id
    const float* srcs[3] = {Wq, Wk, Wv};
    const float* src = srcs[i >> 13] + (size_t)(i & 8191) * 8;
    float4 a = *(const float4*)(src);
    float4 b = *(const float4*)(src + 4);
    us8 u;
    u[0]=f2bf(a.x); u[1]=f2bf(a.y); u[2]=f2bf(a.z); u[3]=f2bf(a.w);
    u[4]=f2bf(b.x); u[5]=f2bf(b.y); u[6]=f2bf(b.z); u[7]=f2bf(b.w);
    *(us8*)(wbf + (size_t)i * 8) = u;
}

// ---------------- QKV projection: LDS double-buffered MFMA GEMM ----------
__global__ __launch_bounds__(512) void qkv_proj(
    const float* __restrict__ x,
    const unsigned short* __restrict__ wbf,
    unsigned short* __restrict__ qo,
    unsigned short* __restrict__ ko,
    unsigned short* __restrict__ vt)
{
    __shared__ float xs[2][64 * 64];            // [buf][row(64)][k(64 fp32)]
    __shared__ unsigned short wsl[2][192 * 64]; // [buf][col(192)][k(64 bf16)]

    const int tid = threadIdx.x;
    const int w = tid >> 6, l = tid & 63, lr = l & 15, lg = l >> 4;
    const int wm = w >> 1, wn = w & 1;
    const int row0 = blockIdx.x * 64;

    f32x4 acc[6];
#pragma unroll
    for (int i = 0; i < 6; i++) acc[i] = (f32x4){0.f, 0.f, 0.f, 0.f};

#define STAGE(buf, t)                                                          \
    {                                                                          \
        const int k0 = (t) * 64;                                               \
        _Pragma("unroll")                                                      \
        for (int i = 0; i < 2; i++) {                                          \
            const int ci = w * 128 + i * 64 + l;       /* 0..1023 */           \
            const int r = ci >> 4, c = ci & 15;                                \
            const float* g = x + (size_t)(row0 + r) * CC + k0 +                \
                             ((c ^ (r & 7)) << 2);                             \
            GLOAD_LDS16(g, &xs[buf][ci * 4]);                                  \
        }                                                                      \
        _Pragma("unroll")                                                      \
        for (int i = 0; i < 3; i++) {                                          \
            const int ci = w * 192 + i * 64 + l;       /* 0..1535 */           \
            const int r = ci >> 3, c = ci & 7;                                 \
            const unsigned short* g = wbf + (size_t)r * CC + k0 +              \
                                      ((c ^ (r & 7)) << 3);                    \
            GLOAD_LDS16(g, &wsl[buf][ci * 8]);                                 \
        }                                                                      \
    }

    STAGE(0, 0);
    __syncthreads();

    for (int t = 0; t < 16; t++) {
        const int buf = t & 1;
        if (t < 15) STAGE(buf ^ 1, t + 1);

        const int ar = wm * 16 + lr;
#pragma unroll
        for (int kk = 0; kk < 2; kk++) {
            const int p0 = (kk * 8 + 2 * lg) ^ (ar & 7);
            const int p1 = (kk * 8 + 2 * lg + 1) ^ (ar & 7);
            float4 a0 = *(const float4*)&xs[buf][ar * 64 + p0 * 4];
            float4 a1 = *(const float4*)&xs[buf][ar * 64 + p1 * 4];
            bf16x8 af;
            af[0]=f2bf(a0.x); af[1]=f2bf(a0.y); af[2]=f2bf(a0.z); af[3]=f2bf(a0.w);
            af[4]=f2bf(a1.x); af[5]=f2bf(a1.y); af[6]=f2bf(a1.z); af[7]=f2bf(a1.w);
#pragma unroll
            for (int nt = 0; nt < 6; nt++) {
                const int col = wn * 96 + nt * 16 + lr;
                const int pos = (kk * 4 + lg) ^ (col & 7);
                bf16x8 bf = *(const bf16x8*)&wsl[buf][col * 64 + pos * 8];
                acc[nt] = __builtin_amdgcn_mfma_f32_16x16x32_bf16(af, bf, acc[nt], 0, 0, 0);
            }
        }
        __syncthreads();
    }

    // q/k epilogue: direct stores
#pragma unroll
    for (int nt = 0; nt < 6; nt++) {
#pragma unroll
        for (int r = 0; r < 4; r++) {
            const int grow = row0 + wm * 16 + lg * 4 + r;
            const int col = wn * 96 + nt * 16 + lr;
            const float val = acc[nt][r];
            if (col < 64) {
                qo[(size_t)grow * HH + col] = f2bf(val * QSCALE);
            } else if (col < 128) {
                ko[(size_t)grow * HH + (col - 64)] = f2bf(val);
            }
        }
    }
    // V epilogue via LDS transpose (2B global scatters were sector-wasteful)
    __syncthreads();
    unsigned short* vtile = (unsigned short*)&xs[0][0];   // reuse 8 KB of xs
    if (wn == 1) {
#pragma unroll
        for (int nt = 2; nt < 6; nt++) {
#pragma unroll
            for (int r = 0; r < 4; r++) {
                const int d = nt * 16 - 32 + lr;         // 0..63
                const int t = wm * 16 + lg * 4 + r;      // 0..63
                vtile[d * 64 + (t ^ ((d & 7) << 3))] = f2bf(acc[nt][r]);
            }
        }
    }
    __syncthreads();
    {
        const int d = tid >> 3, j = tid & 7;
        const int b = row0 >> 11, t0 = row0 & (TT - 1);
        us8 v = *(const us8*)&vtile[d * 64 + ((j * 8) ^ ((d & 7) << 3))];
        *(us8*)(vt + (size_t)(b * HH + d) * VTS + t0 + j * 8) = v;
    }
#undef STAGE
}

// ---------------- split-KV causal attention, swapped-QK^T in-register P ----
// Block = (batch b, q-group G of 4 q-tiles, 256-key chunk c), 4 waves.
// QK^T computed SWAPPED: S^T = mfma(A=K, B=Q), so lane (q=l&15, L=l>>4)
// holds S^T[s=16jt+4L+r][q] — softmax is per-lane (one q per lane, no
// cross-lane ops until the end). P^T fragments for PV are built in-register:
// 8 cvt_pk + 16 ds_bpermute + 8 selects (element j of the ks-frag comes from
// lane (q, 2(L&1)+(j>>2)), reg j&3, of jt=2ks+(L>>1)). O accumulates as O^T
// (d = 16dt+4L+r per lane) -> opart store is 4 contiguous us4 chunks.
// No Ps buffer: LDS 32 KB -> 4 blocks/CU (was 3).
__global__ __launch_bounds__(256, 4) void attn_partial(
    const unsigned short* __restrict__ q,
    const unsigned short* __restrict__ k,
    const unsigned short* __restrict__ vt,
    unsigned short* __restrict__ opart, float* __restrict__ lpart)
{
    __shared__ unsigned short Ks[2][64 * 64];
    __shared__ unsigned short Vs[2][64 * 64];

    const int tid = threadIdx.x;
    const int w = tid >> 6, l = tid & 63, lr = l & 15, lg = l >> 4;

    // decode block -> (b, quad a, d, c); G = 4a+d, qt = 4G+w
    const int bid = blockIdx.x;
    const int b = bid / 144;
    const int r = bid - b * 144;
    int a = 0;
#pragma unroll
    for (int aa = 1; aa < 8; aa++) if (2 * aa * (aa + 1) <= r) a = aa;
    const int rr = r - 2 * a * (a + 1);
    const int d = rr / (a + 1);
    const int c = rr - d * (a + 1);
    const int G = 4 * a + d;
    const int qt = 4 * G + w;
    const int qr0 = qt * 16;
    const int nstage = (c == a) ? (d + 1) : 4;   // uniform across waves
    const int sbase = c * 256;
    const int wu = b * WUB + 8 * a * (a + 1) + (qt & 15) * (a + 1) + c;

    const size_t qbase = ((size_t)b * TT + qr0) * HH;
    bf16x8 qf0 = *(const bf16x8*)(q + qbase + (size_t)lr * HH + lg * 8);
    bf16x8 qf1 = *(const bf16x8*)(q + qbase + (size_t)lr * HH + lg * 8 + 32);

    const unsigned short* kg = k + (size_t)b * TT * HH;
    const unsigned short* vg = vt + (size_t)b * HH * VTS;

    f32x4 o[4];
#pragma unroll
    for (int i = 0; i < 4; i++) o[i] = (f32x4){0.f, 0.f, 0.f, 0.f};
    float lacc = 0.f;
    const int qrow = qr0 + lr;                   // this lane's q row
    // bpermute source addrs: srcA = q + 32*(L&1), srcB = srcA + 16 (bytes*4)
    const int srcA = ((l & 15) | ((l & 16) << 1)) << 2;
    const int srcB = srcA + 64;
    const bool hi = (l & 32) != 0;               // jt-parity select

#define ASTAGE(buf, t)                                                         \
    {                                                                          \
        const int s0_ = sbase + (t) * 64;                                      \
        _Pragma("unroll")                                                      \
        for (int i = 0; i < 2; i++) {                                          \
            const int ci = i * 256 + tid;            /* 0..511 */              \
            const int rK = ci >> 3, cc = ci & 7;                               \
            GLOAD_LDS16(kg + (size_t)(s0_ + rK) * HH + ((cc ^ (rK & 7)) << 3), \
                        &Ks[buf][ci * 8]);                                     \
        }                                                                      \
        _Pragma("unroll")                                                      \
        for (int i = 0; i < 2; i++) {                                          \
            const int ci = i * 256 + tid;                                      \
            const int rV = ci >> 3, cc = ci & 7;                               \
            GLOAD_LDS16(vg + (size_t)rV * VTS + s0_ + ((cc ^ (rV & 7)) << 3),  \
                        &Vs[buf][ci * 8]);                                     \
        }                                                                      \
    }

    ASTAGE(0, 0);
    __syncthreads();

    for (int t = 0; t < nstage; t++) {
        const int buf = t & 1;
        if (t + 1 < nstage) ASTAGE(buf ^ 1, t + 1);
        const int s0 = sbase + t * 64;

        // swapped QK^T -> S^T[s][q]: lane holds s = 16jt+4lg+r for q = lr
        f32x4 s[4];
#pragma unroll
        for (int jt = 0; jt < 4; jt++) {
            const int row = jt * 16 + lr;
            bf16x8 kf0 = *(const bf16x8*)&Ks[buf][row * 64 + ((lg ^ (row & 7)) << 3)];
            bf16x8 kf1 = *(const bf16x8*)&Ks[buf][row * 64 + (((lg + 4) ^ (row & 7)) << 3)];
            f32x4 acc = (f32x4){0.f, 0.f, 0.f, 0.f};
            acc = __builtin_amdgcn_mfma_f32_16x16x32_bf16(kf0, qf0, acc, 0, 0, 0);
            acc = __builtin_amdgcn_mfma_f32_16x16x32_bf16(kf1, qf1, acc, 0, 0, 0);
            s[jt] = acc;
        }

        // p = exp2(s), causal mask, per-lane sum; pack to bf16 pairs
        const bool masked = (s0 + 63 > qr0);
        unsigned int U0[4], U1[4];
#pragma unroll
        for (int jt = 0; jt < 4; jt++) {
#pragma unroll
            for (int rI = 0; rI < 4; rI++) {
                const int key = s0 + jt * 16 + lg * 4 + rI;
                float p = __builtin_exp2f(s[jt][rI]);
                if (masked && key > qrow) p = 0.f;
                lacc += p;
                s[jt][rI] = p;
            }
            U0[jt] = cvtpk(s[jt][0], s[jt][1]);
            U1[jt] = cvtpk(s[jt][2], s[jt][3]);
        }

        // PV (O^T): per ks-half build P^T frag in-register, then 4 MFMA
#pragma unroll
        for (int ks = 0; ks < 2; ks++) {
            const unsigned int e0 = __builtin_amdgcn_ds_bpermute(srcA, U0[2 * ks]);
            const unsigned int o0 = __builtin_amdgcn_ds_bpermute(srcA, U0[2 * ks + 1]);
            const unsigned int e1 = __builtin_amdgcn_ds_bpermute(srcA, U1[2 * ks]);
            const unsigned int o1 = __builtin_amdgcn_ds_bpermute(srcA, U1[2 * ks + 1]);
            const unsigned int e2 = __builtin_amdgcn_ds_bpermute(srcB, U0[2 * ks]);
            const unsigned int o2 = __builtin_amdgcn_ds_bpermute(srcB, U0[2 * ks + 1]);
            const unsigned int e3 = __builtin_amdgcn_ds_bpermute(srcB, U1[2 * ks]);
            const unsigned int o3 = __builtin_amdgcn_ds_bpermute(srcB, U1[2 * ks + 1]);
            union { unsigned int u[4]; bf16x8 v; } pb;
            pb.u[0] = hi ? o0 : e0;
            pb.u[1] = hi ? o1 : e1;
            pb.u[2] = hi ? o2 : e2;
            pb.u[3] = hi ? o3 : e3;
#pragma unroll
            for (int dt = 0; dt < 4; dt++) {
                const int dd = dt * 16 + lr;
                bf16x8 vf = *(const bf16x8*)&Vs[buf][dd * 64 + (((lg + 4 * ks) ^ (dd & 7)) << 3)];
                o[dt] = __builtin_amdgcn_mfma_f32_16x16x32_bf16(vf, pb.v, o[dt], 0, 0, 0);
            }
        }
        __syncthreads();
    }
#undef ASTAGE

    // l: sum across the 4 L-groups holding the same q
    float lsum = lacc;
    lsum += __shfl_xor(lsum, 16);
    lsum += __shfl_xor(lsum, 32);

    // flush partials: lane (q=lr, L=lg) holds O^T[d=16dt+4lg+r][q] ->
    // 4 contiguous us4 (8B) stores into the [q][d] opart layout
#pragma unroll
    for (int dt = 0; dt < 4; dt++) {
        us4 pv;
        pv[0] = f2bf(o[dt][0]); pv[1] = f2bf(o[dt][1]);
        pv[2] = f2bf(o[dt][2]); pv[3] = f2bf(o[dt][3]);
        *(us4*)&opart[((size_t)wu * 16 + lr) * 64 + dt * 16 + lg * 4] = pv;
    }
    if (l < 16) lpart[wu * 16 + l] = lsum;
}

// ---------------- partial reduction + normalize ----------------
__global__ __launch_bounds__(256) void attn_reduce(
    const unsigned short* __restrict__ opart, const float* __restrict__ lpart,
    float* __restrict__ out)
{
    const int bx = blockIdx.x;            // 0..1023
    const int b = bx >> 7, qt = bx & 127;
    const int g = qt >> 4;
    const int base = b * WUB + 8 * g * (g + 1) + (qt - g * 16) * (g + 1);
    const int nch = g + 1;
    const int tid = threadIdx.x;
    const int row = tid >> 4;
    const int d4 = (tid & 15) * 4;

    float4 acc = {0.f, 0.f, 0.f, 0.f};
    float ls = 0.f;
    for (int ch = 0; ch < nch; ch++) {
        us4 v = *(const us4*)&opart[((size_t)(base + ch) * 16 + row) * 64 + d4];
        acc.x += bf2f(v[0]); acc.y += bf2f(v[1]);
        acc.z += bf2f(v[2]); acc.w += bf2f(v[3]);
        ls += lpart[(base + ch) * 16 + row];
    }
    const float inv = 1.f / ls;
    float4 res = {acc.x * inv, acc.y * inv, acc.z * inv, acc.w * inv};
    *(float4*)(out + ((size_t)b * TT + qt * 16 + row) * 64 + d4) = res;
}

extern "C" void kernel_launch(void* const* d_in, const int* in_sizes, int n_in,
                              void* d_out, int out_size, void* d_ws, size_t ws_size,
                              hipStream_t stream) {
    const float* x  = (const float*)d_in[0];
    const float* Wq = (const float*)d_in[1];
    const float* Wk = (const float*)d_in[2];
    const float* Wv = (const float*)d_in[3];
    float* out = (float*)d_out;

    unsigned short* wbf = (unsigned short*)d_ws;                 // 384 KB
    unsigned short* qws = wbf + (size_t)192 * CC;                // 2 MB
    unsigned short* kws = qws + (size_t)BB * TT * HH;            // 2 MB
    unsigned short* vws = kws + (size_t)BB * TT * HH;            // 2.16 MB (padded V^T)
    unsigned short* opart = vws + (size_t)BB * HH * VTS;         // 9.4 MB (bf16)
    float* lpart = (float*)(opart + (size_t)NWU * 16 * 64);      // 295 KB

    wconv<<<dim3(96), dim3(256), 0, stream>>>(Wq, Wk, Wv, wbf);
    qkv_proj<<<dim3(256), dim3(512), 0, stream>>>(x, wbf, qws, kws, vws);
    attn_partial<<<dim3(BB * 144), dim3(256), 0, stream>>>(qws, kws, vws, opart, lpart);
    attn_reduce<<<dim3(BB * 128), dim3(256), 0, stream>>>(opart, lpart, out);
}